// Round 7
// baseline (692.076 us; speedup 1.0000x reference)
//
#include <hip/hip_runtime.h>
#include <hip/hip_bf16.h>
#include <cstdint>

typedef __attribute__((ext_vector_type(8))) short short8;
typedef __attribute__((ext_vector_type(4))) float f32x4;

constexpr int B_ = 2048, E_ = 16, D_ = 1536, H_ = 1024;
constexpr int NHEAD = 256;  // padded head dim: 36(s)+36(o)+132(p)=204 -> 256
constexpr int TOTROWS = B_ * 4;   // 8192 compacted expert-rows
constexpr int MAXTILES = 80;      // sum ceil(c_e/128) <= 8192/128 + 16 = 80
constexpr float EPS_ = 2.220446049250313e-16f;

__device__ __forceinline__ void gload_lds16(const void* g, void* l) {
  __builtin_amdgcn_global_load_lds((const __attribute__((address_space(1))) void*)g,
                                   (__attribute__((address_space(3))) void*)l,
                                   16, 0, 0);
}

// ---------------- zero routing state ----------------
__global__ __launch_bounds__(64) void zero_small(int* __restrict__ p, int n) {
  if ((int)threadIdx.x < n) p[threadIdx.x] = 0;
}

// ---------------- gating: fp32, top-4 + softmax; atomic per-expert counts ----------
__global__ __launch_bounds__(256) void gate_kernel(
    const float* __restrict__ sf, const float* __restrict__ of_,
    const float* __restrict__ ppf, const float* __restrict__ pvf,
    const float* __restrict__ wg, const float* __restrict__ wn,
    const float* __restrict__ noise,
    int* __restrict__ topidx, float* __restrict__ topw, int* __restrict__ counts)
{
  __shared__ float xs[D_];
  __shared__ float sums[32];
  const int b = blockIdx.x, t = threadIdx.x;
  for (int d = t; d < D_; d += 256) {
    float v;
    if (d < 512)       v = sf[b * 512 + d];
    else if (d < 1024) v = of_[b * 512 + (d - 512)];
    else if (d < 1280) v = ppf[b * 256 + (d - 1024)];
    else               v = pvf[b * 256 + (d - 1280)];
    xs[d] = v;
  }
  __syncthreads();
  const int job = t >> 3, sub = t & 7;   // 32 jobs (16 gate + 16 noise), 8 lanes each
  const int e = job & 15;
  const float* w = (job < 16) ? wg : wn;
  float p = 0.f;
  for (int d = sub; d < D_; d += 8) p += xs[d] * w[d * 16 + e];
  p += __shfl_down(p, 4, 8);
  p += __shfl_down(p, 2, 8);
  p += __shfl_down(p, 1, 8);
  if (sub == 0) sums[job] = p;
  __syncthreads();
  if (t == 0) {
    float lg[16];
    for (int i = 0; i < 16; ++i) {
      float z = sums[16 + i];
      float sp = (z > 0.f) ? (z + log1pf(expf(-z))) : log1pf(expf(z));  // softplus
      lg[i] = sums[i] + noise[b * 16 + i] * (sp + 1e-2f);
    }
    float tv[4]; int ti[4];
    unsigned used = 0;
    for (int k = 0; k < 4; ++k) {
      float best = -INFINITY; int bi = 0;
      for (int i = 0; i < 16; ++i)
        if (!((used >> i) & 1u) && lg[i] > best) { best = lg[i]; bi = i; }
      used |= 1u << bi; tv[k] = best; ti[k] = bi;
    }
    float s = 0.f, ex[4];
    for (int k = 0; k < 4; ++k) { ex[k] = expf(tv[k] - tv[0]); s += ex[k]; }
    for (int k = 0; k < 4; ++k) {
      topw[b * 4 + k] = ex[k] / s; topidx[b * 4 + k] = ti[k];
      atomicAdd(&counts[ti[k]], 1);
    }
  }
}

// ---------------- schedule: prefix offsets + M-tile list (single thread) ----------
// Defensively clamped: even corrupted counts cannot overflow tile arrays.
__global__ __launch_bounds__(64) void schedule_kernel(
    const int* __restrict__ counts, int* __restrict__ offsets, int* __restrict__ ntiles,
    int* __restrict__ tile_e, int* __restrict__ tile_rb, int* __restrict__ tile_len)
{
  if (threadIdx.x != 0) return;
  int off = 0, nt = 0;
  for (int e = 0; e < E_; ++e) {
    offsets[e] = off;
    int c = counts[e];
    if (c < 0) c = 0;
    if (c > TOTROWS) c = TOTROWS;           // defensive clamp
    for (int m0 = 0; m0 < c && nt < MAXTILES; m0 += 128) {
      tile_e[nt] = e; tile_rb[nt] = off + m0;
      tile_len[nt] = (c - m0 < 128) ? (c - m0) : 128;
      ++nt;
    }
    off += c;
  }
  offsets[E_] = off;
  *ntiles = nt;
}

// ---------------- build row permutation: slot[b][k] -> compact row ----------------
__global__ __launch_bounds__(256) void build_rows(
    const int* __restrict__ topidx, const int* __restrict__ offsets,
    int* __restrict__ cursor, int* __restrict__ rowtok, int* __restrict__ slot)
{
  const int b = blockIdx.x * 256 + threadIdx.x;
  if (b >= B_) return;
#pragma unroll
  for (int k = 0; k < 4; ++k) {
    const int e = topidx[b * 4 + k];
    const int p = atomicAdd(&cursor[e], 1);
    int row = offsets[e] + p;
    if (row < 0) row = 0;
    if (row >= TOTROWS) row = TOTROWS - 1;  // defensive clamp (unreachable normally)
    rowtok[row] = b;
    slot[b * 4 + k] = row;
  }
}

// ---------------- gather+pack x rows into permuted bf16 matrix ----------------
__global__ __launch_bounds__(256) void gather_x(
    const float* __restrict__ sf, const float* __restrict__ of_,
    const float* __restrict__ ppf, const float* __restrict__ pvf,
    const int* __restrict__ rowtok, __hip_bfloat16* __restrict__ xp)
{
  const int row = blockIdx.x;
  int b = rowtok[row];
  if (b < 0) b = 0;
  if (b >= B_) b = B_ - 1;                  // defensive clamp
  for (int d = threadIdx.x; d < D_; d += 256) {
    float v;
    if (d < 512)       v = sf[b * 512 + d];
    else if (d < 1024) v = of_[b * 512 + (d - 512)];
    else if (d < 1280) v = ppf[b * 256 + (d - 1024)];
    else               v = pvf[b * 256 + (d - 1280)];
    xp[(size_t)row * D_ + d] = __float2bfloat16(v);
  }
}

// ---------------- tiled transpose f32[K][N] -> bf16[N][K], per expert ----------------
__global__ __launch_bounds__(256) void transpose_bf16(
    const float* __restrict__ src, __hip_bfloat16* __restrict__ dst, int K, int N)
{
  __shared__ float tile[32][33];
  const int e = blockIdx.z;
  const int n0 = blockIdx.x * 32, k0 = blockIdx.y * 32;
  const int tx = threadIdx.x, ty = threadIdx.y;
  const float* s = src + (size_t)e * K * N;
  __hip_bfloat16* d = dst + (size_t)e * N * K;
#pragma unroll
  for (int r = 0; r < 4; ++r) {
    const int k = k0 + ty + r * 8;
    tile[ty + r * 8][tx] = s[(size_t)k * N + n0 + tx];
  }
  __syncthreads();
#pragma unroll
  for (int r = 0; r < 4; ++r) {
    const int n = n0 + ty + r * 8;
    d[(size_t)n * K + k0 + tx] = __float2bfloat16(tile[tx][ty + r * 8]);
  }
}

// heads: Ws/Wo/Wp [E][H][{36,36,132}] -> WhT [E][256][H], rows 204..255 zero
__global__ __launch_bounds__(256) void head_transpose(
    const float* __restrict__ Wsp, const float* __restrict__ Wop,
    const float* __restrict__ Wpp, __hip_bfloat16* __restrict__ dst)
{
  __shared__ float tile[32][33];
  const int e = blockIdx.z;
  const int k0 = blockIdx.x * 32;  // over H
  const int n0 = blockIdx.y * 32;  // over padded class dim
  const int tx = threadIdx.x, ty = threadIdx.y;
#pragma unroll
  for (int r = 0; r < 4; ++r) {
    const int k = k0 + ty + r * 8;
    const int n = n0 + tx;
    float v;
    if (n < 36)       v = Wsp[((size_t)e * H_ + k) * 36 + n];
    else if (n < 72)  v = Wop[((size_t)e * H_ + k) * 36 + (n - 36)];
    else if (n < 204) v = Wpp[((size_t)e * H_ + k) * 132 + (n - 72)];
    else              v = 0.f;
    tile[ty + r * 8][tx] = v;
  }
  __syncthreads();
#pragma unroll
  for (int r = 0; r < 4; ++r) {
    const int n = n0 + ty + r * 8;
    dst[((size_t)e * NHEAD + n) * H_ + k0 + tx] = __float2bfloat16(tile[tx][ty + r * 8]);
  }
}

__global__ __launch_bounds__(256) void pack_hbias(
    const float* __restrict__ bs, const float* __restrict__ bo,
    const float* __restrict__ bp, float* __restrict__ hb)
{
  const int e = blockIdx.x, t = threadIdx.x;
  float v = 0.f;
  if (t < 36)       v = bs[e * 36 + t];
  else if (t < 72)  v = bo[e * 36 + (t - 36)];
  else if (t < 204) v = bp[e * 132 + (t - 72)];
  hb[e * NHEAD + t] = v;
}

// ---------------- grouped GEMM over compacted rows: C = A_perm * B[e]^T --------------
// BM=128 (tile list), BN=128, BK=64, 256 threads, m97 structure.
// EPI==0: relu(acc+bias) -> bf16 ; EPI==1: acc+bias -> f32
template <int EPI>
__global__ __launch_bounds__(256) void gemm_sp(
    const int* __restrict__ ntiles, const int* __restrict__ tile_e,
    const int* __restrict__ tile_rb, const int* __restrict__ tile_len,
    const __hip_bfloat16* __restrict__ Ap, int ldA,
    const __hip_bfloat16* __restrict__ Bm, size_t strideB,
    const float* __restrict__ bias,
    void* __restrict__ Cout, int ldC, int K)
{
  __shared__ __align__(16) __hip_bfloat16 lA[128 * 64];
  __shared__ __align__(16) __hip_bfloat16 lB[128 * 64];
  const int ti = blockIdx.x;
  int nt = *ntiles;
  if (nt > MAXTILES) nt = MAXTILES;         // defensive clamp
  if (ti >= nt) return;                      // block-uniform exit
  const int e = tile_e[ti] & 15, rb = tile_rb[ti], L = tile_len[ti];
  const int bn = blockIdx.y;
  const int t = threadIdx.x;
  const int w = t >> 6, lane = t & 63;
  const int wm = w >> 1, wn = w & 1;
  const __hip_bfloat16* Be = Bm + (size_t)e * strideB + (size_t)(bn * 128) * K;
  const int rsub = lane >> 3;         // 0..7  row within wave's 8-row staging slab
  const int csub = (lane & 7) * 8;    // 0..56 bf16 col offset (16B chunks)

  // clamped A staging rows (duplicates masked in epilogue)
  int arows[4];
#pragma unroll
  for (int j = 0; j < 4; ++j) {
    int rloc = j * 32 + w * 8 + rsub;
    int r = rb + (rloc < L ? rloc : L - 1);
    if (r < 0) r = 0;
    if (r >= TOTROWS) r = TOTROWS - 1;       // defensive clamp
    arows[j] = r;
  }

  f32x4 acc[4][4];
#pragma unroll
  for (int m = 0; m < 4; ++m)
#pragma unroll
    for (int n = 0; n < 4; ++n) acc[m][n] = (f32x4){0.f, 0.f, 0.f, 0.f};

  const int KT = K >> 6;
  const int arow = wm * 64 + (lane & 15);
  const int brow = wn * 64 + (lane & 15);
  const int khalf = (lane >> 4) * 8;

  for (int kt = 0; kt < KT; ++kt) {
    const int k0 = kt << 6;
    __syncthreads();  // previous tile's compute done before overwrite
#pragma unroll
    for (int j = 0; j < 4; ++j) {
      const int r = j * 32 + w * 8 + rsub;
      gload_lds16(Ap + (size_t)arows[j] * ldA + (k0 + csub), &lA[j * 2048 + w * 512]);
      gload_lds16(Be + (size_t)r * K + (k0 + csub), &lB[j * 2048 + w * 512]);
    }
    asm volatile("s_waitcnt vmcnt(0)" ::: "memory");
    __syncthreads();
#pragma unroll
    for (int kk = 0; kk < 2; ++kk) {
      short8 af[4], bfr[4];
#pragma unroll
      for (int m = 0; m < 4; ++m)
        af[m] = *(const short8*)&lA[(arow + m * 16) * 64 + kk * 32 + khalf];
#pragma unroll
      for (int n = 0; n < 4; ++n)
        bfr[n] = *(const short8*)&lB[(brow + n * 16) * 64 + kk * 32 + khalf];
#pragma unroll
      for (int m = 0; m < 4; ++m)
#pragma unroll
        for (int n = 0; n < 4; ++n)
          acc[m][n] = __builtin_amdgcn_mfma_f32_16x16x32_bf16(af[m], bfr[n], acc[m][n], 0, 0, 0);
    }
  }

  // epilogue: C/D layout col=lane&15, row=(lane>>4)*4+j ; mask rows >= L
  const int rbase = (lane >> 4) * 4, cbase = lane & 15;
#pragma unroll
  for (int n = 0; n < 4; ++n) {
    const int gcol = bn * 128 + wn * 64 + n * 16 + cbase;
    const float bv = bias[(size_t)e * ldC + gcol];
#pragma unroll
    for (int m = 0; m < 4; ++m) {
      const int rloc0 = wm * 64 + m * 16 + rbase;
#pragma unroll
      for (int j = 0; j < 4; ++j) {
        const int rloc = rloc0 + j;
        if (rloc < L && rb + rloc < TOTROWS) {
          float v = acc[m][n][j] + bv;
          const size_t idx = (size_t)(rb + rloc) * ldC + gcol;
          if (EPI == 0) {
            ((__hip_bfloat16*)Cout)[idx] = __float2bfloat16(v > 0.f ? v : 0.f);
          } else {
            ((float*)Cout)[idx] = v;
          }
        }
      }
    }
  }
}

// ---------------- fused log-softmax + combine over the token's 4 permuted rows ------
__global__ __launch_bounds__(256) void combine_kernel(
    const float* __restrict__ logits, const int* __restrict__ slot,
    const float* __restrict__ topw, float* __restrict__ out)
{
  __shared__ float rows[4][204];
  __shared__ float lse[4][3];
  __shared__ float wk[4];
  const int b = blockIdx.x, t = threadIdx.x;
  if (t < 4) wk[t] = topw[b * 4 + t];
#pragma unroll
  for (int k = 0; k < 4; ++k) {
    int row = slot[b * 4 + k];
    if (row < 0) row = 0;
    if (row >= TOTROWS) row = TOTROWS - 1;  // defensive clamp
    if (t < 204) rows[k][t] = logits[(size_t)row * NHEAD + t];
  }
  __syncthreads();
  const int wv = t >> 6, lane = t & 63;  // wave wv handles expert slot wv
  const int segbase[3] = {0, 36, 72};
  const int segcnt[3] = {36, 36, 132};
  for (int s = 0; s < 3; ++s) {
    float mx = -INFINITY;
    for (int c = lane; c < segcnt[s]; c += 64) mx = fmaxf(mx, rows[wv][segbase[s] + c]);
    for (int o = 32; o > 0; o >>= 1) mx = fmaxf(mx, __shfl_xor(mx, o));
    float sum = 0.f;
    for (int c = lane; c < segcnt[s]; c += 64) sum += expf(rows[wv][segbase[s] + c] - mx);
    for (int o = 32; o > 0; o >>= 1) sum += __shfl_xor(sum, o);
    if (lane == 0) lse[wv][s] = mx + logf(sum);
  }
  __syncthreads();
  if (t < 204) {
    const int seg = t < 36 ? 0 : (t < 72 ? 1 : 2);
    float acc = 0.f;
    for (int k = 0; k < 4; ++k) acc += wk[k] * expf(rows[k][t] - lse[k][seg]);
    if (acc == 0.f) acc = EPS_;
    const float r = logf(acc);
    if (t < 36)      out[b * 36 + t] = r;
    else if (t < 72) out[73728 + b * 36 + (t - 36)] = r;
    else             out[147456 + b * 132 + (t - 72)] = r;
  }
}

extern "C" void kernel_launch(void* const* d_in, const int* in_sizes, int n_in,
                              void* d_out, int out_size, void* d_ws, size_t ws_size,
                              hipStream_t stream)
{
  (void)in_sizes; (void)n_in; (void)out_size; (void)ws_size;
  const float* sf      = (const float*)d_in[0];
  const float* of_     = (const float*)d_in[1];
  const float* ppf     = (const float*)d_in[2];
  const float* pvf     = (const float*)d_in[3];
  const float* w_gate  = (const float*)d_in[4];
  const float* w_noise = (const float*)d_in[5];
  const float* W1      = (const float*)d_in[6];
  const float* b1      = (const float*)d_in[7];
  const float* W2      = (const float*)d_in[8];
  const float* b2      = (const float*)d_in[9];
  const float* Ws      = (const float*)d_in[10];
  const float* bs      = (const float*)d_in[11];
  const float* Wo      = (const float*)d_in[12];
  const float* bo      = (const float*)d_in[13];
  const float* Wp      = (const float*)d_in[14];
  const float* bp      = (const float*)d_in[15];
  const float* noise   = (const float*)d_in[16];

  char* ws = (char*)d_ws;
  size_t off = 0;
  auto take = [&](size_t bytes) -> void* {
    void* p = ws + off; off += (bytes + 255) & ~(size_t)255; return p;
  };
  __hip_bfloat16* W1T = (__hip_bfloat16*)take((size_t)E_ * H_ * D_ * 2);       // 50.3 MB
  __hip_bfloat16* W2T = (__hip_bfloat16*)take((size_t)E_ * H_ * H_ * 2);       // 33.6 MB
  __hip_bfloat16* WhT = (__hip_bfloat16*)take((size_t)E_ * NHEAD * H_ * 2);    // 8.4 MB
  float* hbias        = (float*)take((size_t)E_ * NHEAD * 4);
  __hip_bfloat16* xp  = (__hip_bfloat16*)take((size_t)TOTROWS * D_ * 2);       // 25.2 MB
  __hip_bfloat16* h1p = (__hip_bfloat16*)take((size_t)TOTROWS * H_ * 2);       // 16.8 MB
  __hip_bfloat16* h2p = (__hip_bfloat16*)take((size_t)TOTROWS * H_ * 2);       // 16.8 MB
  float* logitsp      = (float*)take((size_t)TOTROWS * NHEAD * 4);             // 8.4 MB
  int* counts         = (int*)take(64 * 4);
  int* cursor         = (int*)take(64 * 4);
  int* offsets        = (int*)take(64 * 4);
  int* ntiles         = (int*)take(64 * 4);
  int* tile_e         = (int*)take(MAXTILES * 4);
  int* tile_rb        = (int*)take(MAXTILES * 4);
  int* tile_len       = (int*)take(MAXTILES * 4);
  int* topidx         = (int*)take((size_t)B_ * 4 * 4);
  float* topw         = (float*)take((size_t)B_ * 4 * 4);
  int* rowtok         = (int*)take((size_t)TOTROWS * 4);
  int* slot           = (int*)take((size_t)B_ * 4 * 4);

  zero_small<<<1, 64, 0, stream>>>(counts, E_);
  zero_small<<<1, 64, 0, stream>>>(cursor, E_);
  gate_kernel<<<B_, 256, 0, stream>>>(sf, of_, ppf, pvf, w_gate, w_noise, noise,
                                      topidx, topw, counts);
  schedule_kernel<<<1, 64, 0, stream>>>(counts, offsets, ntiles, tile_e, tile_rb, tile_len);
  build_rows<<<(B_ + 255) / 256, 256, 0, stream>>>(topidx, offsets, cursor, rowtok, slot);
  gather_x<<<TOTROWS, 256, 0, stream>>>(sf, of_, ppf, pvf, rowtok, xp);

  transpose_bf16<<<dim3(H_ / 32, D_ / 32, E_), dim3(32, 8), 0, stream>>>(W1, W1T, D_, H_);
  transpose_bf16<<<dim3(H_ / 32, H_ / 32, E_), dim3(32, 8), 0, stream>>>(W2, W2T, H_, H_);
  head_transpose<<<dim3(H_ / 32, NHEAD / 32, E_), dim3(32, 8), 0, stream>>>(Ws, Wo, Wp, WhT);
  pack_hbias<<<E_, 256, 0, stream>>>(bs, bo, bp, hbias);

  gemm_sp<0><<<dim3(MAXTILES, H_ / 128), 256, 0, stream>>>(
      ntiles, tile_e, tile_rb, tile_len, xp, D_, W1T, (size_t)H_ * D_, b1, h1p, H_, D_);
  gemm_sp<0><<<dim3(MAXTILES, H_ / 128), 256, 0, stream>>>(
      ntiles, tile_e, tile_rb, tile_len, h1p, H_, W2T, (size_t)H_ * H_, b2, h2p, H_, H_);
  gemm_sp<1><<<dim3(MAXTILES, NHEAD / 128), 256, 0, stream>>>(
      ntiles, tile_e, tile_rb, tile_len, h2p, H_, WhT, (size_t)NHEAD * H_, hbias, logitsp, NHEAD, H_);

  combine_kernel<<<B_, 256, 0, stream>>>(logitsp, slot, topw, (float*)d_out);
}

// Round 8
// 567.407 us; speedup vs baseline: 1.2197x; 1.2197x over previous
//
#include <hip/hip_runtime.h>
#include <hip/hip_bf16.h>
#include <cstdint>

typedef __attribute__((ext_vector_type(8))) short short8;
typedef __attribute__((ext_vector_type(4))) float f32x4;

constexpr int B_ = 2048, E_ = 16, D_ = 1536, H_ = 1024;
constexpr int NHEAD = 256;  // padded head dim: 36(s)+36(o)+132(p)=204 -> 256
constexpr int TOTROWS = B_ * 4;   // 8192 compacted expert-rows
constexpr int MAXTILES = 80;      // sum ceil(c_e/128) <= 8192/128 + 16 = 80
constexpr float EPS_ = 2.220446049250313e-16f;

__device__ __forceinline__ void gload_lds16(const void* g, void* l) {
  __builtin_amdgcn_global_load_lds((const __attribute__((address_space(1))) void*)g,
                                   (__attribute__((address_space(3))) void*)l,
                                   16, 0, 0);
}

// ---------------- zero routing state ----------------
__global__ __launch_bounds__(64) void zero_small(int* __restrict__ p, int n) {
  if ((int)threadIdx.x < n) p[threadIdx.x] = 0;
}

// ---------------- gate logits: [B,32] = x @ [w_gate | w_noise], coalesced -----------
// 256 blocks x 256 threads; 8 tokens/block staged in LDS; thread = (token, out-col).
__global__ __launch_bounds__(256) void gate_logits(
    const float* __restrict__ sf, const float* __restrict__ of_,
    const float* __restrict__ ppf, const float* __restrict__ pvf,
    const float* __restrict__ wg, const float* __restrict__ wn,
    float* __restrict__ logits_all)
{
  __shared__ float xs[8][D_];   // 48 KB
  const int b0 = blockIdx.x * 8;
  const int t = threadIdx.x;
  for (int i = t; i < 8 * (D_ / 4); i += 256) {
    const int row = i / (D_ / 4);
    const int c4 = i % (D_ / 4);
    const int b = b0 + row;
    const int d = c4 * 4;
    float4 v;
    if (d < 512)       v = ((const float4*)(sf  + (size_t)b * 512))[c4];
    else if (d < 1024) v = ((const float4*)(of_ + (size_t)b * 512))[c4 - 128];
    else if (d < 1280) v = ((const float4*)(ppf + (size_t)b * 256))[c4 - 256];
    else               v = ((const float4*)(pvf + (size_t)b * 256))[c4 - 320];
    *(float4*)&xs[row][d] = v;
  }
  __syncthreads();
  const int tok = t >> 5, out = t & 31;
  const int col = out & 15;
  const float* __restrict__ w = (out < 16) ? wg : wn;
  float a0 = 0.f, a1 = 0.f, a2 = 0.f, a3 = 0.f;
#pragma unroll 4
  for (int d = 0; d < D_; d += 4) {
    a0 += xs[tok][d + 0] * w[(d + 0) * 16 + col];
    a1 += xs[tok][d + 1] * w[(d + 1) * 16 + col];
    a2 += xs[tok][d + 2] * w[(d + 2) * 16 + col];
    a3 += xs[tok][d + 3] * w[(d + 3) * 16 + col];
  }
  logits_all[(size_t)(b0 + tok) * 32 + out] = (a0 + a1) + (a2 + a3);
}

// ---------------- top-4 + softmax per token (one thread/token), LDS histogram -------
__global__ __launch_bounds__(256) void topk_kernel(
    const float* __restrict__ logits_all, const float* __restrict__ noise,
    int* __restrict__ topidx, float* __restrict__ topw, int* __restrict__ counts)
{
  __shared__ int hist[E_];
  const int t = threadIdx.x;
  if (t < E_) hist[t] = 0;
  __syncthreads();
  const int b = blockIdx.x * 256 + t;
  if (b < B_) {
    float lg[16];
#pragma unroll
    for (int i = 0; i < 16; ++i) {
      const float clean = logits_all[(size_t)b * 32 + i];
      const float z = logits_all[(size_t)b * 32 + 16 + i];
      const float sp = (z > 0.f) ? (z + log1pf(expf(-z))) : log1pf(expf(z));  // softplus
      lg[i] = clean + noise[b * 16 + i] * (sp + 1e-2f);
    }
    float tv[4]; int ti[4];
    unsigned used = 0;
#pragma unroll
    for (int k = 0; k < 4; ++k) {
      float best = -INFINITY; int bi = 0;
#pragma unroll
      for (int i = 0; i < 16; ++i)
        if (!((used >> i) & 1u) && lg[i] > best) { best = lg[i]; bi = i; }
      used |= 1u << bi; tv[k] = best; ti[k] = bi;
    }
    float s = 0.f, ex[4];
#pragma unroll
    for (int k = 0; k < 4; ++k) { ex[k] = expf(tv[k] - tv[0]); s += ex[k]; }
#pragma unroll
    for (int k = 0; k < 4; ++k) {
      topw[b * 4 + k] = ex[k] / s; topidx[b * 4 + k] = ti[k];
      atomicAdd(&hist[ti[k]], 1);
    }
  }
  __syncthreads();
  if (t < E_) atomicAdd(&counts[t], hist[t]);
}

// ---------------- schedule: prefix offsets + M-tile list (single thread) ----------
// Defensively clamped: even corrupted counts cannot overflow tile arrays.
__global__ __launch_bounds__(64) void schedule_kernel(
    const int* __restrict__ counts, int* __restrict__ offsets, int* __restrict__ ntiles,
    int* __restrict__ tile_e, int* __restrict__ tile_rb, int* __restrict__ tile_len)
{
  if (threadIdx.x != 0) return;
  int off = 0, nt = 0;
  for (int e = 0; e < E_; ++e) {
    offsets[e] = off;
    int c = counts[e];
    if (c < 0) c = 0;
    if (c > TOTROWS) c = TOTROWS;           // defensive clamp
    for (int m0 = 0; m0 < c && nt < MAXTILES; m0 += 128) {
      tile_e[nt] = e; tile_rb[nt] = off + m0;
      tile_len[nt] = (c - m0 < 128) ? (c - m0) : 128;
      ++nt;
    }
    off += c;
  }
  offsets[E_] = off;
  *ntiles = nt;
}

// ---------------- build row permutation: slot[b][k] -> compact row ----------------
__global__ __launch_bounds__(256) void build_rows(
    const int* __restrict__ topidx, const int* __restrict__ offsets,
    int* __restrict__ cursor, int* __restrict__ rowtok, int* __restrict__ slot)
{
  const int b = blockIdx.x * 256 + threadIdx.x;
  if (b >= B_) return;
#pragma unroll
  for (int k = 0; k < 4; ++k) {
    const int e = topidx[b * 4 + k];
    const int p = atomicAdd(&cursor[e], 1);
    int row = offsets[e] + p;
    if (row < 0) row = 0;
    if (row >= TOTROWS) row = TOTROWS - 1;  // defensive clamp (unreachable normally)
    rowtok[row] = b;
    slot[b * 4 + k] = row;
  }
}

// ---------------- gather+pack x rows into permuted bf16 matrix ----------------
__global__ __launch_bounds__(256) void gather_x(
    const float* __restrict__ sf, const float* __restrict__ of_,
    const float* __restrict__ ppf, const float* __restrict__ pvf,
    const int* __restrict__ rowtok, __hip_bfloat16* __restrict__ xp)
{
  const int row = blockIdx.x;
  int b = rowtok[row];
  if (b < 0) b = 0;
  if (b >= B_) b = B_ - 1;                  // defensive clamp
  for (int d = threadIdx.x; d < D_; d += 256) {
    float v;
    if (d < 512)       v = sf[b * 512 + d];
    else if (d < 1024) v = of_[b * 512 + (d - 512)];
    else if (d < 1280) v = ppf[b * 256 + (d - 1024)];
    else               v = pvf[b * 256 + (d - 1280)];
    xp[(size_t)row * D_ + d] = __float2bfloat16(v);
  }
}

// ---------------- tiled transpose f32[K][N] -> bf16[N][K], per expert ----------------
__global__ __launch_bounds__(256) void transpose_bf16(
    const float* __restrict__ src, __hip_bfloat16* __restrict__ dst, int K, int N)
{
  __shared__ float tile[32][33];
  const int e = blockIdx.z;
  const int n0 = blockIdx.x * 32, k0 = blockIdx.y * 32;
  const int tx = threadIdx.x, ty = threadIdx.y;
  const float* s = src + (size_t)e * K * N;
  __hip_bfloat16* d = dst + (size_t)e * N * K;
#pragma unroll
  for (int r = 0; r < 4; ++r) {
    const int k = k0 + ty + r * 8;
    tile[ty + r * 8][tx] = s[(size_t)k * N + n0 + tx];
  }
  __syncthreads();
#pragma unroll
  for (int r = 0; r < 4; ++r) {
    const int n = n0 + ty + r * 8;
    d[(size_t)n * K + k0 + tx] = __float2bfloat16(tile[tx][ty + r * 8]);
  }
}

// heads: Ws/Wo/Wp [E][H][{36,36,132}] -> WhT [E][256][H], rows 204..255 zero
__global__ __launch_bounds__(256) void head_transpose(
    const float* __restrict__ Wsp, const float* __restrict__ Wop,
    const float* __restrict__ Wpp, __hip_bfloat16* __restrict__ dst)
{
  __shared__ float tile[32][33];
  const int e = blockIdx.z;
  const int k0 = blockIdx.x * 32;  // over H
  const int n0 = blockIdx.y * 32;  // over padded class dim
  const int tx = threadIdx.x, ty = threadIdx.y;
#pragma unroll
  for (int r = 0; r < 4; ++r) {
    const int k = k0 + ty + r * 8;
    const int n = n0 + tx;
    float v;
    if (n < 36)       v = Wsp[((size_t)e * H_ + k) * 36 + n];
    else if (n < 72)  v = Wop[((size_t)e * H_ + k) * 36 + (n - 36)];
    else if (n < 204) v = Wpp[((size_t)e * H_ + k) * 132 + (n - 72)];
    else              v = 0.f;
    tile[ty + r * 8][tx] = v;
  }
  __syncthreads();
#pragma unroll
  for (int r = 0; r < 4; ++r) {
    const int n = n0 + ty + r * 8;
    dst[((size_t)e * NHEAD + n) * H_ + k0 + tx] = __float2bfloat16(tile[tx][ty + r * 8]);
  }
}

__global__ __launch_bounds__(256) void pack_hbias(
    const float* __restrict__ bs, const float* __restrict__ bo,
    const float* __restrict__ bp, float* __restrict__ hb)
{
  const int e = blockIdx.x, t = threadIdx.x;
  float v = 0.f;
  if (t < 36)       v = bs[e * 36 + t];
  else if (t < 72)  v = bo[e * 36 + (t - 36)];
  else if (t < 204) v = bp[e * 132 + (t - 72)];
  hb[e * NHEAD + t] = v;
}

// ---------------- grouped GEMM over compacted rows: C = A_perm * B[e]^T --------------
// BM=128 (tile list), BN=128, BK=64, 256 threads, m97 structure.
// EPI==0: relu(acc+bias) -> bf16 ; EPI==1: acc+bias -> f32
template <int EPI>
__global__ __launch_bounds__(256) void gemm_sp(
    const int* __restrict__ ntiles, const int* __restrict__ tile_e,
    const int* __restrict__ tile_rb, const int* __restrict__ tile_len,
    const __hip_bfloat16* __restrict__ Ap, int ldA,
    const __hip_bfloat16* __restrict__ Bm, size_t strideB,
    const float* __restrict__ bias,
    void* __restrict__ Cout, int ldC, int K)
{
  __shared__ __align__(16) __hip_bfloat16 lA[128 * 64];
  __shared__ __align__(16) __hip_bfloat16 lB[128 * 64];
  const int ti = blockIdx.x;
  int nt = *ntiles;
  if (nt > MAXTILES) nt = MAXTILES;         // defensive clamp
  if (ti >= nt) return;                      // block-uniform exit
  const int e = tile_e[ti] & 15, rb = tile_rb[ti], L = tile_len[ti];
  const int bn = blockIdx.y;
  const int t = threadIdx.x;
  const int w = t >> 6, lane = t & 63;
  const int wm = w >> 1, wn = w & 1;
  const __hip_bfloat16* Be = Bm + (size_t)e * strideB + (size_t)(bn * 128) * K;
  const int rsub = lane >> 3;         // 0..7  row within wave's 8-row staging slab
  const int csub = (lane & 7) * 8;    // 0..56 bf16 col offset (16B chunks)

  // clamped A staging rows (duplicates masked in epilogue)
  int arows[4];
#pragma unroll
  for (int j = 0; j < 4; ++j) {
    int rloc = j * 32 + w * 8 + rsub;
    int r = rb + (rloc < L ? rloc : L - 1);
    if (r < 0) r = 0;
    if (r >= TOTROWS) r = TOTROWS - 1;       // defensive clamp
    arows[j] = r;
  }

  f32x4 acc[4][4];
#pragma unroll
  for (int m = 0; m < 4; ++m)
#pragma unroll
    for (int n = 0; n < 4; ++n) acc[m][n] = (f32x4){0.f, 0.f, 0.f, 0.f};

  const int KT = K >> 6;
  const int arow = wm * 64 + (lane & 15);
  const int brow = wn * 64 + (lane & 15);
  const int khalf = (lane >> 4) * 8;

  for (int kt = 0; kt < KT; ++kt) {
    const int k0 = kt << 6;
    __syncthreads();  // previous tile's compute done before overwrite
#pragma unroll
    for (int j = 0; j < 4; ++j) {
      const int r = j * 32 + w * 8 + rsub;
      gload_lds16(Ap + (size_t)arows[j] * ldA + (k0 + csub), &lA[j * 2048 + w * 512]);
      gload_lds16(Be + (size_t)r * K + (k0 + csub), &lB[j * 2048 + w * 512]);
    }
    asm volatile("s_waitcnt vmcnt(0)" ::: "memory");
    __syncthreads();
#pragma unroll
    for (int kk = 0; kk < 2; ++kk) {
      short8 af[4], bfr[4];
#pragma unroll
      for (int m = 0; m < 4; ++m)
        af[m] = *(const short8*)&lA[(arow + m * 16) * 64 + kk * 32 + khalf];
#pragma unroll
      for (int n = 0; n < 4; ++n)
        bfr[n] = *(const short8*)&lB[(brow + n * 16) * 64 + kk * 32 + khalf];
#pragma unroll
      for (int m = 0; m < 4; ++m)
#pragma unroll
        for (int n = 0; n < 4; ++n)
          acc[m][n] = __builtin_amdgcn_mfma_f32_16x16x32_bf16(af[m], bfr[n], acc[m][n], 0, 0, 0);
    }
  }

  // epilogue: C/D layout col=lane&15, row=(lane>>4)*4+j ; mask rows >= L
  const int rbase = (lane >> 4) * 4, cbase = lane & 15;
#pragma unroll
  for (int n = 0; n < 4; ++n) {
    const int gcol = bn * 128 + wn * 64 + n * 16 + cbase;
    const float bv = bias[(size_t)e * ldC + gcol];
#pragma unroll
    for (int m = 0; m < 4; ++m) {
      const int rloc0 = wm * 64 + m * 16 + rbase;
#pragma unroll
      for (int j = 0; j < 4; ++j) {
        const int rloc = rloc0 + j;
        if (rloc < L && rb + rloc < TOTROWS) {
          float v = acc[m][n][j] + bv;
          const size_t idx = (size_t)(rb + rloc) * ldC + gcol;
          if (EPI == 0) {
            ((__hip_bfloat16*)Cout)[idx] = __float2bfloat16(v > 0.f ? v : 0.f);
          } else {
            ((float*)Cout)[idx] = v;
          }
        }
      }
    }
  }
}

// ---------------- fused log-softmax + combine over the token's 4 permuted rows ------
__global__ __launch_bounds__(256) void combine_kernel(
    const float* __restrict__ logits, const int* __restrict__ slot,
    const float* __restrict__ topw, float* __restrict__ out)
{
  __shared__ float rows[4][204];
  __shared__ float lse[4][3];
  __shared__ float wk[4];
  const int b = blockIdx.x, t = threadIdx.x;
  if (t < 4) wk[t] = topw[b * 4 + t];
#pragma unroll
  for (int k = 0; k < 4; ++k) {
    int row = slot[b * 4 + k];
    if (row < 0) row = 0;
    if (row >= TOTROWS) row = TOTROWS - 1;  // defensive clamp
    if (t < 204) rows[k][t] = logits[(size_t)row * NHEAD + t];
  }
  __syncthreads();
  const int wv = t >> 6, lane = t & 63;  // wave wv handles expert slot wv
  const int segbase[3] = {0, 36, 72};
  const int segcnt[3] = {36, 36, 132};
  for (int s = 0; s < 3; ++s) {
    float mx = -INFINITY;
    for (int c = lane; c < segcnt[s]; c += 64) mx = fmaxf(mx, rows[wv][segbase[s] + c]);
    for (int o = 32; o > 0; o >>= 1) mx = fmaxf(mx, __shfl_xor(mx, o));
    float sum = 0.f;
    for (int c = lane; c < segcnt[s]; c += 64) sum += expf(rows[wv][segbase[s] + c] - mx);
    for (int o = 32; o > 0; o >>= 1) sum += __shfl_xor(sum, o);
    if (lane == 0) lse[wv][s] = mx + logf(sum);
  }
  __syncthreads();
  if (t < 204) {
    const int seg = t < 36 ? 0 : (t < 72 ? 1 : 2);
    float acc = 0.f;
    for (int k = 0; k < 4; ++k) acc += wk[k] * expf(rows[k][t] - lse[k][seg]);
    if (acc == 0.f) acc = EPS_;
    const float r = logf(acc);
    if (t < 36)      out[b * 36 + t] = r;
    else if (t < 72) out[73728 + b * 36 + (t - 36)] = r;
    else             out[147456 + b * 132 + (t - 72)] = r;
  }
}

extern "C" void kernel_launch(void* const* d_in, const int* in_sizes, int n_in,
                              void* d_out, int out_size, void* d_ws, size_t ws_size,
                              hipStream_t stream)
{
  (void)in_sizes; (void)n_in; (void)out_size; (void)ws_size;
  const float* sf      = (const float*)d_in[0];
  const float* of_     = (const float*)d_in[1];
  const float* ppf     = (const float*)d_in[2];
  const float* pvf     = (const float*)d_in[3];
  const float* w_gate  = (const float*)d_in[4];
  const float* w_noise = (const float*)d_in[5];
  const float* W1      = (const float*)d_in[6];
  const float* b1      = (const float*)d_in[7];
  const float* W2      = (const float*)d_in[8];
  const float* b2      = (const float*)d_in[9];
  const float* Ws      = (const float*)d_in[10];
  const float* bs      = (const float*)d_in[11];
  const float* Wo      = (const float*)d_in[12];
  const float* bo      = (const float*)d_in[13];
  const float* Wp      = (const float*)d_in[14];
  const float* bp      = (const float*)d_in[15];
  const float* noise   = (const float*)d_in[16];

  char* ws = (char*)d_ws;
  size_t off = 0;
  auto take = [&](size_t bytes) -> void* {
    void* p = ws + off; off += (bytes + 255) & ~(size_t)255; return p;
  };
  __hip_bfloat16* W1T = (__hip_bfloat16*)take((size_t)E_ * H_ * D_ * 2);       // 50.3 MB
  __hip_bfloat16* W2T = (__hip_bfloat16*)take((size_t)E_ * H_ * H_ * 2);       // 33.6 MB
  __hip_bfloat16* WhT = (__hip_bfloat16*)take((size_t)E_ * NHEAD * H_ * 2);    // 8.4 MB
  float* hbias        = (float*)take((size_t)E_ * NHEAD * 4);
  __hip_bfloat16* xp  = (__hip_bfloat16*)take((size_t)TOTROWS * D_ * 2);       // 25.2 MB
  __hip_bfloat16* h1p = (__hip_bfloat16*)take((size_t)TOTROWS * H_ * 2);       // 16.8 MB
  __hip_bfloat16* h2p = (__hip_bfloat16*)take((size_t)TOTROWS * H_ * 2);       // 16.8 MB
  float* logitsp      = (float*)take((size_t)TOTROWS * NHEAD * 4);             // 8.4 MB
  float* logits_all   = (float*)take((size_t)B_ * 32 * 4);
  int* counts         = (int*)take(64 * 4);
  int* cursor         = (int*)take(64 * 4);
  int* offsets        = (int*)take(64 * 4);
  int* ntiles         = (int*)take(64 * 4);
  int* tile_e         = (int*)take(MAXTILES * 4);
  int* tile_rb        = (int*)take(MAXTILES * 4);
  int* tile_len       = (int*)take(MAXTILES * 4);
  int* topidx         = (int*)take((size_t)B_ * 4 * 4);
  float* topw         = (float*)take((size_t)B_ * 4 * 4);
  int* rowtok         = (int*)take((size_t)TOTROWS * 4);
  int* slot           = (int*)take((size_t)B_ * 4 * 4);

  zero_small<<<1, 64, 0, stream>>>(counts, E_);
  zero_small<<<1, 64, 0, stream>>>(cursor, E_);
  gate_logits<<<B_ / 8, 256, 0, stream>>>(sf, of_, ppf, pvf, w_gate, w_noise, logits_all);
  topk_kernel<<<B_ / 256, 256, 0, stream>>>(logits_all, noise, topidx, topw, counts);
  schedule_kernel<<<1, 64, 0, stream>>>(counts, offsets, ntiles, tile_e, tile_rb, tile_len);
  build_rows<<<(B_ + 255) / 256, 256, 0, stream>>>(topidx, offsets, cursor, rowtok, slot);
  gather_x<<<TOTROWS, 256, 0, stream>>>(sf, of_, ppf, pvf, rowtok, xp);

  transpose_bf16<<<dim3(H_ / 32, D_ / 32, E_), dim3(32, 8), 0, stream>>>(W1, W1T, D_, H_);
  transpose_bf16<<<dim3(H_ / 32, H_ / 32, E_), dim3(32, 8), 0, stream>>>(W2, W2T, H_, H_);
  head_transpose<<<dim3(H_ / 32, NHEAD / 32, E_), dim3(32, 8), 0, stream>>>(Ws, Wo, Wp, WhT);
  pack_hbias<<<E_, 256, 0, stream>>>(bs, bo, bp, hbias);

  gemm_sp<0><<<dim3(MAXTILES, H_ / 128), 256, 0, stream>>>(
      ntiles, tile_e, tile_rb, tile_len, xp, D_, W1T, (size_t)H_ * D_, b1, h1p, H_, D_);
  gemm_sp<0><<<dim3(MAXTILES, H_ / 128), 256, 0, stream>>>(
      ntiles, tile_e, tile_rb, tile_len, h1p, H_, W2T, (size_t)H_ * H_, b2, h2p, H_, H_);
  gemm_sp<1><<<dim3(MAXTILES, NHEAD / 128), 256, 0, stream>>>(
      ntiles, tile_e, tile_rb, tile_len, h2p, H_, WhT, (size_t)NHEAD * H_, hbias, logitsp, NHEAD, H_);

  combine_kernel<<<B_, 256, 0, stream>>>(logitsp, slot, topw, (float*)d_out);
}

// Round 10
// 529.109 us; speedup vs baseline: 1.3080x; 1.0724x over previous
//
#include <hip/hip_runtime.h>
#include <hip/hip_bf16.h>
#include <cstdint>

typedef __attribute__((ext_vector_type(8))) short short8;
typedef __attribute__((ext_vector_type(4))) float f32x4;

constexpr int B_ = 2048, E_ = 16, D_ = 1536, H_ = 1024;
constexpr int NHEAD = 256;  // padded head dim: 36(s)+36(o)+132(p)=204 -> 256
constexpr int TOTROWS = B_ * 4;   // 8192 compacted expert-rows
constexpr int MAXTILES = 144;     // BM=64: sum ceil(c_e/64) <= 8177/64+1 + 15 = 144
constexpr float EPS_ = 2.220446049250313e-16f;

__device__ __forceinline__ void gload_lds16(const void* g, void* l) {
  __builtin_amdgcn_global_load_lds((const __attribute__((address_space(1))) void*)g,
                                   (__attribute__((address_space(3))) void*)l,
                                   16, 0, 0);
}

// ---------------- zero routing state (counts + cursor, 256B apart) ----------------
__global__ __launch_bounds__(128) void zero128(int* __restrict__ p) {
  p[threadIdx.x] = 0;   // covers counts[0..63] and cursor[0..63]
}

// ---------------- pack x (concat) to bf16, token order ----------------
__global__ __launch_bounds__(256) void pack_x(
    const float* __restrict__ sf, const float* __restrict__ of_,
    const float* __restrict__ ppf, const float* __restrict__ pvf,
    __hip_bfloat16* __restrict__ xb)
{
  const int b = blockIdx.x;
  for (int d = threadIdx.x; d < D_; d += 256) {
    float v;
    if (d < 512)       v = sf[b * 512 + d];
    else if (d < 1024) v = of_[b * 512 + (d - 512)];
    else if (d < 1280) v = ppf[b * 256 + (d - 1024)];
    else               v = pvf[b * 256 + (d - 1280)];
    xb[(size_t)b * D_ + d] = __float2bfloat16(v);
  }
}

// ---------------- gate logits: [B,32] = x @ [w_gate | w_noise], coalesced -----------
__global__ __launch_bounds__(256) void gate_logits(
    const float* __restrict__ sf, const float* __restrict__ of_,
    const float* __restrict__ ppf, const float* __restrict__ pvf,
    const float* __restrict__ wg, const float* __restrict__ wn,
    float* __restrict__ logits_all)
{
  __shared__ float xs[8][D_];   // 48 KB
  const int b0 = blockIdx.x * 8;
  const int t = threadIdx.x;
  for (int i = t; i < 8 * (D_ / 4); i += 256) {
    const int row = i / (D_ / 4);
    const int c4 = i % (D_ / 4);
    const int b = b0 + row;
    const int d = c4 * 4;
    float4 v;
    if (d < 512)       v = ((const float4*)(sf  + (size_t)b * 512))[c4];
    else if (d < 1024) v = ((const float4*)(of_ + (size_t)b * 512))[c4 - 128];
    else if (d < 1280) v = ((const float4*)(ppf + (size_t)b * 256))[c4 - 256];
    else               v = ((const float4*)(pvf + (size_t)b * 256))[c4 - 320];
    *(float4*)&xs[row][d] = v;
  }
  __syncthreads();
  const int tok = t >> 5, out = t & 31;
  const int col = out & 15;
  const float* __restrict__ w = (out < 16) ? wg : wn;
  float a0 = 0.f, a1 = 0.f, a2 = 0.f, a3 = 0.f;
#pragma unroll 4
  for (int d = 0; d < D_; d += 4) {
    a0 += xs[tok][d + 0] * w[(d + 0) * 16 + col];
    a1 += xs[tok][d + 1] * w[(d + 1) * 16 + col];
    a2 += xs[tok][d + 2] * w[(d + 2) * 16 + col];
    a3 += xs[tok][d + 3] * w[(d + 3) * 16 + col];
  }
  logits_all[(size_t)(b0 + tok) * 32 + out] = (a0 + a1) + (a2 + a3);
}

// ---------------- top-4 + softmax per token (one thread/token), LDS histogram -------
__global__ __launch_bounds__(256) void topk_kernel(
    const float* __restrict__ logits_all, const float* __restrict__ noise,
    int* __restrict__ topidx, float* __restrict__ topw, int* __restrict__ counts)
{
  __shared__ int hist[E_];
  const int t = threadIdx.x;
  if (t < E_) hist[t] = 0;
  __syncthreads();
  const int b = blockIdx.x * 256 + t;
  if (b < B_) {
    float lg[16];
#pragma unroll
    for (int i = 0; i < 16; ++i) {
      const float clean = logits_all[(size_t)b * 32 + i];
      const float z = logits_all[(size_t)b * 32 + 16 + i];
      const float sp = (z > 0.f) ? (z + log1pf(expf(-z))) : log1pf(expf(z));  // softplus
      lg[i] = clean + noise[b * 16 + i] * (sp + 1e-2f);
    }
    float tv[4]; int ti[4];
    unsigned used = 0;
#pragma unroll
    for (int k = 0; k < 4; ++k) {
      float best = -INFINITY; int bi = 0;
#pragma unroll
      for (int i = 0; i < 16; ++i)
        if (!((used >> i) & 1u) && lg[i] > best) { best = lg[i]; bi = i; }
      used |= 1u << bi; tv[k] = best; ti[k] = bi;
    }
    float s = 0.f, ex[4];
#pragma unroll
    for (int k = 0; k < 4; ++k) { ex[k] = expf(tv[k] - tv[0]); s += ex[k]; }
#pragma unroll
    for (int k = 0; k < 4; ++k) {
      topw[b * 4 + k] = ex[k] / s; topidx[b * 4 + k] = ti[k];
      atomicAdd(&hist[ti[k]], 1);
    }
  }
  __syncthreads();
  if (t < E_) atomicAdd(&counts[t], hist[t]);
}

// ---------------- schedule: prefix offsets + M-tile list (BM=64), clamped ----------
__global__ __launch_bounds__(64) void schedule_kernel(
    const int* __restrict__ counts, int* __restrict__ offsets, int* __restrict__ ntiles,
    int* __restrict__ tile_e, int* __restrict__ tile_rb, int* __restrict__ tile_len)
{
  if (threadIdx.x != 0) return;
  int off = 0, nt = 0;
  for (int e = 0; e < E_; ++e) {
    offsets[e] = off;
    int c = counts[e];
    if (c < 0) c = 0;
    if (c > TOTROWS) c = TOTROWS;           // defensive clamp
    for (int m0 = 0; m0 < c && nt < MAXTILES; m0 += 64) {
      tile_e[nt] = e; tile_rb[nt] = off + m0;
      tile_len[nt] = (c - m0 < 64) ? (c - m0) : 64;
      ++nt;
    }
    off += c;
  }
  offsets[E_] = off;
  *ntiles = nt;
}

// ---------------- build row permutation: slot[b][k] -> compact row ----------------
__global__ __launch_bounds__(256) void build_rows(
    const int* __restrict__ topidx, const int* __restrict__ offsets,
    int* __restrict__ cursor, int* __restrict__ rowtok, int* __restrict__ slot)
{
  const int b = blockIdx.x * 256 + threadIdx.x;
  if (b >= B_) return;
#pragma unroll
  for (int k = 0; k < 4; ++k) {
    const int e = topidx[b * 4 + k];
    const int p = atomicAdd(&cursor[e], 1);
    int row = offsets[e] + p;
    if (row < 0) row = 0;
    if (row >= TOTROWS) row = TOTROWS - 1;  // defensive clamp (unreachable normally)
    rowtok[row] = b;
    slot[b * 4 + k] = row;
  }
}

// ---------------- tiled transpose f32[K][N] -> bf16[N][K], per expert ----------------
__global__ __launch_bounds__(256) void transpose_bf16(
    const float* __restrict__ src, __hip_bfloat16* __restrict__ dst, int K, int N)
{
  __shared__ float tile[32][33];
  const int e = blockIdx.z;
  const int n0 = blockIdx.x * 32, k0 = blockIdx.y * 32;
  const int tx = threadIdx.x, ty = threadIdx.y;
  const float* s = src + (size_t)e * K * N;
  __hip_bfloat16* d = dst + (size_t)e * N * K;
#pragma unroll
  for (int r = 0; r < 4; ++r) {
    const int k = k0 + ty + r * 8;
    tile[ty + r * 8][tx] = s[(size_t)k * N + n0 + tx];
  }
  __syncthreads();
#pragma unroll
  for (int r = 0; r < 4; ++r) {
    const int n = n0 + ty + r * 8;
    d[(size_t)n * K + k0 + tx] = __float2bfloat16(tile[tx][ty + r * 8]);
  }
}

// heads: Ws/Wo/Wp [E][H][{36,36,132}] -> WhT [E][256][H], rows 204..255 zero
__global__ __launch_bounds__(256) void head_transpose(
    const float* __restrict__ Wsp, const float* __restrict__ Wop,
    const float* __restrict__ Wpp, __hip_bfloat16* __restrict__ dst)
{
  __shared__ float tile[32][33];
  const int e = blockIdx.z;
  const int k0 = blockIdx.x * 32;  // over H
  const int n0 = blockIdx.y * 32;  // over padded class dim
  const int tx = threadIdx.x, ty = threadIdx.y;
#pragma unroll
  for (int r = 0; r < 4; ++r) {
    const int k = k0 + ty + r * 8;
    const int n = n0 + tx;
    float v;
    if (n < 36)       v = Wsp[((size_t)e * H_ + k) * 36 + n];
    else if (n < 72)  v = Wop[((size_t)e * H_ + k) * 36 + (n - 36)];
    else if (n < 204) v = Wpp[((size_t)e * H_ + k) * 132 + (n - 72)];
    else              v = 0.f;
    tile[ty + r * 8][tx] = v;
  }
  __syncthreads();
#pragma unroll
  for (int r = 0; r < 4; ++r) {
    const int n = n0 + ty + r * 8;
    dst[((size_t)e * NHEAD + n) * H_ + k0 + tx] = __float2bfloat16(tile[tx][ty + r * 8]);
  }
}

__global__ __launch_bounds__(256) void pack_hbias(
    const float* __restrict__ bs, const float* __restrict__ bo,
    const float* __restrict__ bp, float* __restrict__ hb)
{
  const int e = blockIdx.x, t = threadIdx.x;
  float v = 0.f;
  if (t < 36)       v = bs[e * 36 + t];
  else if (t < 72)  v = bo[e * 36 + (t - 36)];
  else if (t < 204) v = bp[e * 132 + (t - 72)];
  hb[e * NHEAD + t] = v;
}

// ---------------- grouped GEMM, BM=64 BN=128 BK=64, 256 thr (2x2 waves, 32x64/wave) --
// GATHER==1: A rows indirect via rowtok (GEMM1 reads packed tokens xb directly).
// EPI==0: relu(acc+bias) -> bf16 ; EPI==1: acc+bias -> f32
template <int EPI, int GATHER>
__global__ __launch_bounds__(256) void gemm_sp(
    const int* __restrict__ ntiles, const int* __restrict__ tile_e,
    const int* __restrict__ tile_rb, const int* __restrict__ tile_len,
    const int* __restrict__ rowtok,
    const __hip_bfloat16* __restrict__ Ap, int ldA,
    const __hip_bfloat16* __restrict__ Bm, size_t strideB,
    const float* __restrict__ bias,
    void* __restrict__ Cout, int ldC, int K)
{
  __shared__ __align__(16) __hip_bfloat16 lA[64 * 64];    //  8 KB
  __shared__ __align__(16) __hip_bfloat16 lB[128 * 64];   // 16 KB
  const int ti = blockIdx.x;
  int nt = *ntiles;
  if (nt > MAXTILES) nt = MAXTILES;         // defensive clamp
  if (ti >= nt) return;                      // block-uniform exit
  const int e = tile_e[ti] & 15, rb = tile_rb[ti], L = tile_len[ti];   // L in 1..64
  const int bn = blockIdx.y;
  const int t = threadIdx.x;
  const int w = t >> 6, lane = t & 63;
  const int wm = w >> 1, wn = w & 1;        // wave out-tile: rows wm*32.., cols wn*64..
  const __hip_bfloat16* Be = Bm + (size_t)e * strideB + (size_t)(bn * 128) * K;
  const int srow = t >> 3;                  // 0..31 staging row within slab
  const int scol = (t & 7) * 8;             // bf16 col offset (16B chunks)

  // A source rows: 2 slabs of 32; clamped duplicates masked in epilogue
  int asrc[2];
#pragma unroll
  for (int j = 0; j < 2; ++j) {
    const int rloc = j * 32 + srow;
    int r = rb + (rloc < L ? rloc : L - 1);
    if (r < 0) r = 0;
    if (r >= TOTROWS) r = TOTROWS - 1;       // defensive clamp
    if (GATHER) {
      r = rowtok[r];
      if (r < 0) r = 0;
      if (r >= B_) r = B_ - 1;               // defensive clamp
    }
    asrc[j] = r;
  }

  f32x4 acc[2][4];
#pragma unroll
  for (int m = 0; m < 2; ++m)
#pragma unroll
    for (int n = 0; n < 4; ++n) acc[m][n] = (f32x4){0.f, 0.f, 0.f, 0.f};

  const int KT = K >> 6;
  const int arow = wm * 32 + (lane & 15);
  const int brow = wn * 64 + (lane & 15);
  const int khalf = (lane >> 4) * 8;

  for (int kt = 0; kt < KT; ++kt) {
    const int k0 = kt << 6;
    __syncthreads();  // previous tile's compute done before overwrite
#pragma unroll
    for (int j = 0; j < 2; ++j)
      gload_lds16(Ap + (size_t)asrc[j] * ldA + (k0 + scol), lA + j * 2048 + t * 8);
#pragma unroll
    for (int j = 0; j < 4; ++j)
      gload_lds16(Be + (size_t)(j * 32 + srow) * K + (k0 + scol), lB + j * 2048 + t * 8);
    asm volatile("s_waitcnt vmcnt(0)" ::: "memory");
    __syncthreads();
#pragma unroll
    for (int kk = 0; kk < 2; ++kk) {
      short8 af[2], bfr[4];
#pragma unroll
      for (int m = 0; m < 2; ++m)
        af[m] = *(const short8*)&lA[(arow + m * 16) * 64 + kk * 32 + khalf];
#pragma unroll
      for (int n = 0; n < 4; ++n)
        bfr[n] = *(const short8*)&lB[(brow + n * 16) * 64 + kk * 32 + khalf];
#pragma unroll
      for (int m = 0; m < 2; ++m)
#pragma unroll
        for (int n = 0; n < 4; ++n)
          acc[m][n] = __builtin_amdgcn_mfma_f32_16x16x32_bf16(af[m], bfr[n], acc[m][n], 0, 0, 0);
    }
  }

  // epilogue: C/D layout col=lane&15, row=(lane>>4)*4+j ; mask rows >= L
  const int rbase = (lane >> 4) * 4, cbase = lane & 15;
#pragma unroll
  for (int n = 0; n < 4; ++n) {
    const int gcol = bn * 128 + wn * 64 + n * 16 + cbase;
    const float bv = bias[(size_t)e * ldC + gcol];
#pragma unroll
    for (int m = 0; m < 2; ++m) {
      const int rloc0 = wm * 32 + m * 16 + rbase;
#pragma unroll
      for (int j = 0; j < 4; ++j) {
        const int rloc = rloc0 + j;
        if (rloc < L && rb + rloc < TOTROWS) {
          float v = acc[m][n][j] + bv;
          const size_t idx = (size_t)(rb + rloc) * ldC + gcol;
          if (EPI == 0) {
            ((__hip_bfloat16*)Cout)[idx] = __float2bfloat16(v > 0.f ? v : 0.f);
          } else {
            ((float*)Cout)[idx] = v;
          }
        }
      }
    }
  }
}

// ---------------- fused log-softmax + combine over the token's 4 permuted rows ------
__global__ __launch_bounds__(256) void combine_kernel(
    const float* __restrict__ logits, const int* __restrict__ slot,
    const float* __restrict__ topw, float* __restrict__ out)
{
  __shared__ float rows[4][204];
  __shared__ float lse[4][3];
  __shared__ float wk[4];
  const int b = blockIdx.x, t = threadIdx.x;
  if (t < 4) wk[t] = topw[b * 4 + t];
#pragma unroll
  for (int k = 0; k < 4; ++k) {
    int row = slot[b * 4 + k];
    if (row < 0) row = 0;
    if (row >= TOTROWS) row = TOTROWS - 1;  // defensive clamp
    if (t < 204) rows[k][t] = logits[(size_t)row * NHEAD + t];
  }
  __syncthreads();
  const int wv = t >> 6, lane = t & 63;  // wave wv handles expert slot wv
  const int segbase[3] = {0, 36, 72};
  const int segcnt[3] = {36, 36, 132};
  for (int s = 0; s < 3; ++s) {
    float mx = -INFINITY;
    for (int c = lane; c < segcnt[s]; c += 64) mx = fmaxf(mx, rows[wv][segbase[s] + c]);
    for (int o = 32; o > 0; o >>= 1) mx = fmaxf(mx, __shfl_xor(mx, o));
    float sum = 0.f;
    for (int c = lane; c < segcnt[s]; c += 64) sum += expf(rows[wv][segbase[s] + c] - mx);
    for (int o = 32; o > 0; o >>= 1) sum += __shfl_xor(sum, o);
    if (lane == 0) lse[wv][s] = mx + logf(sum);
  }
  __syncthreads();
  if (t < 204) {
    const int seg = t < 36 ? 0 : (t < 72 ? 1 : 2);
    float acc = 0.f;
    for (int k = 0; k < 4; ++k) acc += wk[k] * expf(rows[k][t] - lse[k][seg]);
    if (acc == 0.f) acc = EPS_;
    const float r = logf(acc);
    if (t < 36)      out[b * 36 + t] = r;
    else if (t < 72) out[73728 + b * 36 + (t - 36)] = r;
    else             out[147456 + b * 132 + (t - 72)] = r;
  }
}

extern "C" void kernel_launch(void* const* d_in, const int* in_sizes, int n_in,
                              void* d_out, int out_size, void* d_ws, size_t ws_size,
                              hipStream_t stream)
{
  (void)in_sizes; (void)n_in; (void)out_size; (void)ws_size;
  const float* sf      = (const float*)d_in[0];
  const float* of_     = (const float*)d_in[1];
  const float* ppf     = (const float*)d_in[2];
  const float* pvf     = (const float*)d_in[3];
  const float* w_gate  = (const float*)d_in[4];
  const float* w_noise = (const float*)d_in[5];
  const float* W1      = (const float*)d_in[6];
  const float* b1      = (const float*)d_in[7];
  const float* W2      = (const float*)d_in[8];
  const float* b2      = (const float*)d_in[9];
  const float* Ws      = (const float*)d_in[10];
  const float* bs      = (const float*)d_in[11];
  const float* Wo      = (const float*)d_in[12];
  const float* bo      = (const float*)d_in[13];
  const float* Wp      = (const float*)d_in[14];
  const float* bp      = (const float*)d_in[15];
  const float* noise   = (const float*)d_in[16];

  char* ws = (char*)d_ws;
  size_t off = 0;
  auto take = [&](size_t bytes) -> void* {
    void* p = ws + off; off += (bytes + 255) & ~(size_t)255; return p;
  };
  __hip_bfloat16* W1T = (__hip_bfloat16*)take((size_t)E_ * H_ * D_ * 2);       // 50.3 MB
  __hip_bfloat16* W2T = (__hip_bfloat16*)take((size_t)E_ * H_ * H_ * 2);       // 33.6 MB
  __hip_bfloat16* WhT = (__hip_bfloat16*)take((size_t)E_ * NHEAD * H_ * 2);    // 8.4 MB
  float* hbias        = (float*)take((size_t)E_ * NHEAD * 4);
  __hip_bfloat16* xb  = (__hip_bfloat16*)take((size_t)B_ * D_ * 2);            // 6.3 MB
  __hip_bfloat16* h1p = (__hip_bfloat16*)take((size_t)TOTROWS * H_ * 2);       // 16.8 MB
  __hip_bfloat16* h2p = (__hip_bfloat16*)take((size_t)TOTROWS * H_ * 2);       // 16.8 MB
  float* logitsp      = (float*)take((size_t)TOTROWS * NHEAD * 4);             // 8.4 MB
  float* logits_all   = (float*)take((size_t)B_ * 32 * 4);
  int* counts         = (int*)take(64 * 4);     // adjacent to cursor (256B apart)
  int* cursor         = (int*)take(64 * 4);
  int* offsets        = (int*)take(64 * 4);
  int* ntiles         = (int*)take(64 * 4);
  int* tile_e         = (int*)take(MAXTILES * 4);
  int* tile_rb        = (int*)take(MAXTILES * 4);
  int* tile_len       = (int*)take(MAXTILES * 4);
  int* topidx         = (int*)take((size_t)B_ * 4 * 4);
  float* topw         = (float*)take((size_t)B_ * 4 * 4);
  int* rowtok         = (int*)take((size_t)TOTROWS * 4);
  int* slot           = (int*)take((size_t)B_ * 4 * 4);

  zero128<<<1, 128, 0, stream>>>(counts);   // zeroes counts + cursor
  gate_logits<<<B_ / 8, 256, 0, stream>>>(sf, of_, ppf, pvf, w_gate, w_noise, logits_all);
  topk_kernel<<<B_ / 256, 256, 0, stream>>>(logits_all, noise, topidx, topw, counts);
  schedule_kernel<<<1, 64, 0, stream>>>(counts, offsets, ntiles, tile_e, tile_rb, tile_len);
  build_rows<<<(B_ + 255) / 256, 256, 0, stream>>>(topidx, offsets, cursor, rowtok, slot);
  pack_x<<<B_, 256, 0, stream>>>(sf, of_, ppf, pvf, xb);

  transpose_bf16<<<dim3(H_ / 32, D_ / 32, E_), dim3(32, 8), 0, stream>>>(W1, W1T, D_, H_);
  transpose_bf16<<<dim3(H_ / 32, H_ / 32, E_), dim3(32, 8), 0, stream>>>(W2, W2T, H_, H_);
  head_transpose<<<dim3(H_ / 32, NHEAD / 32, E_), dim3(32, 8), 0, stream>>>(Ws, Wo, Wp, WhT);
  pack_hbias<<<E_, 256, 0, stream>>>(bs, bo, bp, hbias);

  gemm_sp<0, 1><<<dim3(MAXTILES, H_ / 128), 256, 0, stream>>>(
      ntiles, tile_e, tile_rb, tile_len, rowtok, xb, D_, W1T, (size_t)H_ * D_, b1,
      h1p, H_, D_);
  gemm_sp<0, 0><<<dim3(MAXTILES, H_ / 128), 256, 0, stream>>>(
      ntiles, tile_e, tile_rb, tile_len, rowtok, h1p, H_, W2T, (size_t)H_ * H_, b2,
      h2p, H_, H_);
  gemm_sp<1, 0><<<dim3(MAXTILES, NHEAD / 128), 256, 0, stream>>>(
      ntiles, tile_e, tile_rb, tile_len, rowtok, h2p, H_, WhT, (size_t)NHEAD * H_, hbias,
      logitsp, NHEAD, H_);

  combine_kernel<<<B_, 256, 0, stream>>>(logitsp, slot, topw, (float*)d_out);
}